// Round 3
// baseline (11004.808 us; speedup 1.0000x reference)
//
#include <hip/hip_runtime.h>

typedef _Float16 f16;
typedef _Float16 f16x4 __attribute__((ext_vector_type(4)));
typedef _Float16 f16x8 __attribute__((ext_vector_type(8)));
typedef float    f32x4 __attribute__((ext_vector_type(4)));

#define NN 1024
#define NT 12
#define NHOR 12
#define ROWS (NN*64)                      // 65536 (n*64+b)
#define MATH (1024*1024)                  // halves per support matrix
static const long SLOT = (long)NN*4096;   // one diffusion slot (n,(b,u)) = 4M halves

__device__ __forceinline__ int sw4(int row){ return (row ^ (row>>2)) & 3; }

// interleave position within each 32-window: chunk c holds k = [4c..4c+3, 16+4c..16+4c+3]
__device__ __forceinline__ int ilvpos(int k){
  int r = k & 31;
  return (k & ~31) + ((r & 12) << 1) + (r & 3) + ((r & 16) >> 2);
}

// stage NR rows x 32 halves (window k0) into LDS, 16B chunks XOR'd by sw4(row).
template<int NR>
__device__ __forceinline__ void stage(f16* lds, const f16* src, int ldk, int k0, int tid){
  #pragma unroll
  for (int ic=0; ic<NR/64; ++ic){
    const int c = tid + ic*256;
    const int row = c>>2, c4 = c&3;
    const f16* g = src + (long)row*ldk + k0 + ((c4 ^ sw4(row))<<3);
    f16* d = lds + c*8;
    __builtin_amdgcn_global_load_lds((const __attribute__((address_space(1))) void*)g,
                                     (__attribute__((address_space(3))) void*)d, 16, 0, 0);
  }
}

// fragment from interleaved rows: one b128
__device__ __forceinline__ f16x8 fragI(const f16* lds, int row, int rq){
  return *(const f16x8*)&lds[row*32 + ((rq ^ sw4(row))<<3)];
}

// fragment from natural rows: two b64
__device__ __forceinline__ f16x8 fragN(const f16* lds, int row, int lk){
  const int s = sw4(row);
  const int cl = (lk>>3) ^ s, ch = (2|(lk>>3)) ^ s;
  f16x4 lo = *(const f16x4*)&lds[row*32 + (cl<<3) + (lk&7)];
  f16x4 hi = *(const f16x4*)&lds[row*32 + (ch<<3) + (lk&7)];
  f16x8 r; r[0]=lo[0];r[1]=lo[1];r[2]=lo[2];r[3]=lo[3];
  r[4]=hi[0];r[5]=hi[1];r[6]=hi[2];r[7]=hi[3];
  return r;
}

// ---------------------------------------------------------------- diffusion GEMM
// D[bu][c=(q,n)] = sum_m A[bu][m] * B[(q,n)][m]; A read natural-[m][bu] via tr, or ilv rows.
struct DiffP {
  const f16* A0; const f16* A1;
  const f16* B;                 // interleaved rows [4096][1024]
  f16* out0; f16* out1;
  int nt0;                      // row tiles in part0
  int a0tr, a1tr;               // 1: A natural [m][4096] via tr-read; 0: ilv rows [*][1024]
  int mode_x;                   // part1 epilogue: 0 = slots (SLOT), 2 = Dx0 (ROWS)
  int wsq;                      // 1: out = 2*acc - I, natural [.][1024]
};

__global__ __launch_bounds__(256) void gemm_diff(DiffP p) {
  __shared__ f16 As[128*32];
  __shared__ f16 Bs[128*32];
  const int tid=threadIdx.x, l=tid&63, w=tid>>6;
  const int rq=l>>4, ro=l&15, lk=rq*4;
  const int rt=blockIdx.x, ct=blockIdx.y;
  const int part = (rt >= p.nt0);
  const int rtl  = part ? (rt - p.nt0) : rt;
  const int atr  = part ? p.a1tr : p.a0tr;
  const f16* Ab  = part ? p.A1 : p.A0;
  const f16* Bbase = p.B + (long)ct*128*1024;
  const int wm=(w>>1)*64, wc=(w&1)*64;
  // tr-gather per-thread source mapping (n_t, bu_t) for LDS-linear dest
  const int n_t  = ((tid>>5)&1)*16 + ((tid>>3)&3)*4 + ((tid>>1)&3);
  const int but0 = ((tid>>6)&3)*16 + (tid&1)*8;
  const f16* gtr = Ab + (long)n_t*4096 + (long)rtl*128 + but0;
  const f16* Ailv = Ab + (long)rtl*128*1024;
  f32x4 acc[4][4] = {};
  for (int k0=0; k0<1024; k0+=32) {
    if (atr) {
      const f16* g = gtr + (long)k0*4096;
      __builtin_amdgcn_global_load_lds((const __attribute__((address_space(1))) void*)g,
                                       (__attribute__((address_space(3))) void*)(As + tid*8), 16, 0, 0);
      __builtin_amdgcn_global_load_lds((const __attribute__((address_space(1))) void*)(g + 64),
                                       (__attribute__((address_space(3))) void*)(As + (tid+256)*8), 16, 0, 0);
    } else {
      stage<128>(As, Ailv, 1024, k0, tid);
    }
    stage<128>(Bs, Bbase, 1024, k0, tid);
    __syncthreads();
    f16x8 a[4], b[4];
    if (atr) {
      const unsigned abase = (unsigned)(size_t)(__attribute__((address_space(3))) f16*)&As[0]
                           + (unsigned)((w>>1)*4096 + l*8);
      f16x4 tlo[4], thi[4];
      #pragma unroll
      for (int i=0;i<4;i++){
        asm volatile("ds_read_b64_tr_b16 %0, %1 offset:%2" : "=v"(tlo[i]) : "v"(abase), "i"(i*1024));
        asm volatile("ds_read_b64_tr_b16 %0, %1 offset:%2" : "=v"(thi[i]) : "v"(abase), "i"(i*1024+512));
      }
      asm volatile("s_waitcnt lgkmcnt(0)" ::: "memory");
      __builtin_amdgcn_sched_barrier(0);
      #pragma unroll
      for (int i=0;i<4;i++){
        f16x8 t2; t2[0]=tlo[i][0];t2[1]=tlo[i][1];t2[2]=tlo[i][2];t2[3]=tlo[i][3];
        t2[4]=thi[i][0];t2[5]=thi[i][1];t2[6]=thi[i][2];t2[7]=thi[i][3];
        a[i]=t2;
      }
    } else {
      #pragma unroll
      for (int i=0;i<4;i++) a[i] = fragI(As, wm + i*16 + ro, rq);
    }
    #pragma unroll
    for (int j=0;j<4;j++) b[j] = fragI(Bs, wc + j*16 + ro, rq);
    #pragma unroll
    for (int i=0;i<4;i++)
      #pragma unroll
      for (int j=0;j<4;j++)   // swapped: acc[i][j][e] = elem(Arow=wm+i*16+ro, Brow=wc+j*16+lk+e)
        acc[i][j] = __builtin_amdgcn_mfma_f32_16x16x32_f16(b[j], a[i], acc[i][j], 0,0,0);
    __syncthreads();
  }
  if (p.wsq) {
    #pragma unroll
    for (int i=0;i<4;i++){
      const long rg = (long)rt*128 + wm + i*16 + ro;
      #pragma unroll
      for (int j=0;j<4;j++){
        const int cb = ct*128 + wc + j*16 + lk;
        f16x4 sv;
        #pragma unroll
        for (int e=0;e<4;e++) sv[e] = (f16)(2.f*acc[i][j][e] - ((rg==(long)(cb+e))?1.f:0.f));
        *(f16x4*)&p.out0[rg*1024 + cb] = sv;
      }
    }
    return;
  }
  f16* ob = part ? p.out1 : p.out0;
  const int mode = part ? p.mode_x : 0;
  const long rowbase = (long)rtl*128;
  #pragma unroll
  for (int i=0;i<4;i++){
    const int bu = wm + i*16 + ro;
    if (mode==2 && bu>=64) continue;
    #pragma unroll
    for (int j=0;j<4;j++){
      const int cb = ct*128 + wc + j*16 + lk;
      #pragma unroll
      for (int e=0;e<4;e++){
        const int c = cb + e, q = c>>10, n = c&1023;
        const f16 v = (f16)acc[i][j][e];
        if (mode==0) ob[(long)q*SLOT + (long)n*4096 + rowbase + bu] = v;
        else         ob[(long)q*ROWS + n*64 + bu] = v;
      }
    }
  }
}

// ---------------------------------------------------------------- cell GEMMs
struct Tab5 { const f16* p[5]; };
struct CellP {
  Tab5 ta, tb, xq;
  const f16 *wa, *wb, *wx0;   // wa/wb: [O][320] k-interleaved; wx0: [5][O] natural
  const float* bias;
  const float* h32in;
  f16* rh; float* u32;
  float* h32io; f16* h16io;
  int nseg, xf1;
};

template<int O, int GATE>
__global__ __launch_bounds__(256) void cell_gemm(CellP p) {
  constexpr int FC = O/32;
  __shared__ f16 As[128*32];
  __shared__ f16 Bs[O*32];
  const int tid=threadIdx.x, l=tid&63, w=tid>>6;
  const int rq=l>>4, ro=l&15, lk=rq*4;
  const int wm=(w>>1)*64, wc=(w&1)*(O/2);
  f32x4 acc[4][FC] = {};
  const long r0 = (long)blockIdx.x*128;
  const int Ktot = p.nseg*320;
  for (int kg=0; kg<Ktot; kg+=32) {
    const int seg = (kg>=320) ? 1 : 0;
    const int kk  = kg - seg*320;
    const int q = kk>>6, kq = kk&63;
    const f16* asrc = (seg ? p.tb.p[q] : p.ta.p[q]) + r0*64;
    const f16* wsrc = seg ? p.wb : p.wa;
    stage<128>(As, asrc, 64, kq, tid);
    stage<O>(Bs, wsrc, 320, kk, tid);
    __syncthreads();
    f16x8 a[4], b[FC];
    #pragma unroll
    for (int i=0;i<4;i++) a[i] = fragN(As, wm + i*16 + ro, lk);
    #pragma unroll
    for (int j=0;j<FC;j++) b[j] = fragI(Bs, wc + j*16 + ro, rq);
    #pragma unroll
    for (int i=0;i<4;i++)
      #pragma unroll
      for (int j=0;j<FC;j++)
        acc[i][j] = __builtin_amdgcn_mfma_f32_16x16x32_f16(a[i], b[j], acc[i][j], 0,0,0);
    __syncthreads();
  }
  #pragma unroll
  for (int i=0;i<4;i++) {
    #pragma unroll
    for (int e=0;e<4;e++) {
      const long rg = r0 + wm + i*16 + rq*4 + e;
      float xv[5];
      if (p.xf1) {
        #pragma unroll
        for (int q2=0;q2<5;q2++) xv[q2] = (float)p.xq.p[q2][rg];
      }
      #pragma unroll
      for (int j=0;j<FC;j++) {
        const int col = wc + j*16 + ro;
        float v = acc[i][j][e] + p.bias[col];
        if (p.xf1) {
          #pragma unroll
          for (int q2=0;q2<5;q2++) v += xv[q2] * (float)p.wx0[q2*O + col];
        }
        if (GATE) {
          const float s = 1.f/(1.f + __expf(-v));
          if (col < 64) p.rh[rg*64 + col] = (f16)(s * p.h32in[rg*64 + col]);
          else          p.u32[rg*64 + (col-64)] = s;
        } else {
          const float cc = tanhf(v);
          const float u  = p.u32[rg*64 + col];
          const float h  = p.h32io[rg*64 + col];
          const float hn = u*h + (1.f-u)*cc;
          p.h32io[rg*64 + col] = hn;
          p.h16io[rg*64 + col] = (f16)hn;
        }
      }
    }
  }
}

// ---------------------------------------------------------------- setup kernels
__global__ __launch_bounds__(256) void k_transpose(const f16* in, f16* out, int R, int C) {
  __shared__ f16 T[64*66];
  const long rb = (long)blockIdx.x*64, cb = (long)blockIdx.y*64;
  const int t = threadIdx.x;
  #pragma unroll
  for (int it=0; it<2; ++it) {
    const int r = (t>>3) + it*32, c8 = (t&7)*8;
    f16x8 v = *(const f16x8*)(in + (rb+r)*C + cb + c8);
    *(f16x8*)&T[r*66 + c8] = v;
  }
  __syncthreads();
  #pragma unroll
  for (int it=0; it<2; ++it) {
    const int c = (t>>3) + it*32, r8 = (t&7)*8;
    f16x8 v;
    #pragma unroll
    for (int j=0;j<8;j++) v[j] = T[(r8+j)*66 + c];
    *(f16x8*)(out + (cb+c)*R + rb + r8) = v;
  }
}

__global__ void k_cast_sup(const float* s, f16* o) {
  long i = (long)blockIdx.x*256 + threadIdx.x;
  if (i < 2LL*MATH) o[i] = (f16)s[i];
}

__global__ void k_ilv(const f16* in, f16* out) {
  int i = blockIdx.x*256 + threadIdx.x;
  if (i >= MATH) return;
  int r = i>>10, k = i&1023;
  out[(long)r*1024 + ilvpos(k)] = in[i];
}

__global__ void k_pack_x(const float* in, f16* xe, f16* xet) {
  int i = blockIdx.x*256 + threadIdx.x;
  if (i >= NT*ROWS) return;
  int t = i / ROWS, r = i % ROWS, n = r>>6, b = r&63;
  float v = in[(long)b*NN*NT + (long)n*NT + t];
  xe[i] = (f16)v;
  xet[(long)t*131072 + (long)b*1024 + ilvpos(n)] = (f16)v;
}

// src [5][f][O] f32 -> wh_t [O][320] ilv (h rows); x rows -> wx_t [O][320] ilv or wx0 [5][O]
__global__ void k_split_w_t(const float* src, f16* wh_t, f16* wxA, int f, int xf, int O) {
  int i = blockIdx.x*256 + threadIdx.x;
  if (i >= 5*f*O) return;
  int o = i % O, rr = i / O, q = rr / f, ff = rr % f;
  f16 v = (f16)src[i];
  if (ff < xf) {
    if (xf == 1) wxA[q*O + o] = v;
    else         wxA[(long)o*320 + q*64 + ilvpos(ff)] = v;
  } else {
    wh_t[(long)o*320 + q*64 + ilvpos(ff - xf)] = v;
  }
}

__global__ void k_proj(const float* h32, const float* pw, const float* pb,
                       float* out, f16* xdec, f16* xdect) {
  int r = blockIdx.x*256 + threadIdx.x;
  if (r >= ROWS) return;
  float acc = pb[0];
  const float* hp = h32 + (long)r*64;
  #pragma unroll
  for (int k=0;k<64;k++) acc += hp[k]*pw[k];
  int n = r>>6, b = r&63;
  out[(long)b*NN + n] = acc;
  xdec[r] = (f16)acc;
  xdect[(long)b*1024 + ilvpos(n)] = (f16)acc;
}

// ---------------------------------------------------------------- driver
extern "C" void kernel_launch(void* const* d_in, const int* in_sizes, int n_in,
                              void* d_out, int out_size, void* d_ws, size_t ws_size,
                              hipStream_t stream) {
  (void)in_sizes; (void)n_in; (void)out_size; (void)ws_size;
  const float* inputs = (const float*)d_in[0];
  const float* sup    = (const float*)d_in[1];
  const float* gwp[4] = {(const float*)d_in[2], (const float*)d_in[6], (const float*)d_in[10], (const float*)d_in[14]};
  const float* gbp[4] = {(const float*)d_in[3], (const float*)d_in[7], (const float*)d_in[11], (const float*)d_in[15]};
  const float* cwp[4] = {(const float*)d_in[4], (const float*)d_in[8], (const float*)d_in[12], (const float*)d_in[16]};
  const float* cbp[4] = {(const float*)d_in[5], (const float*)d_in[9], (const float*)d_in[13], (const float*)d_in[17]};
  const float* pw = (const float*)d_in[18];
  const float* pb = (const float*)d_in[19];
  float* out = (float*)d_out;

  char* base = (char*)d_ws; size_t off = 0;
  auto alloc = [&](size_t bytes)->void* { void* p = base + off; off += (bytes + 255) & ~(size_t)255; return p; };
  f16* W16int = (f16*)alloc(4LL*MATH*2);        // [A0, 2A0^2-I, A1, 2A1^2-I] k-interleaved
  f16* xenc   = (f16*)alloc((long)NT*ROWS*2);
  f16* xet    = (f16*)alloc((long)NT*131072*2); // [t][128 b-pad][1024 n-ilv]
  f16* xdec   = (f16*)alloc((long)ROWS*2);
  f16* xdect  = (f16*)alloc(131072L*2);
  f16*  h16[2]  = {(f16*)alloc((long)ROWS*64*2),  (f16*)alloc((long)ROWS*64*2)};
  float* h32[2] = {(float*)alloc((long)ROWS*64*4), (float*)alloc((long)ROWS*64*4)};
  float* u32 = (float*)alloc((long)ROWS*64*4);
  f16* rh    = (f16*)alloc((long)ROWS*64*2);
  f16* Dh    = (f16*)alloc(4*SLOT*2);
  f16* Dx    = (f16*)alloc(4*SLOT*2);
  f16* Dx0   = (f16*)alloc(4LL*ROWS*2);
  f16 *gwh[4], *gwx[4], *cwh[4], *cwx[4];
  for (int i=0;i<4;i++) {
    gwh[i]=(f16*)alloc(128L*320*2); gwx[i]=(f16*)alloc(128L*320*2);
    cwh[i]=(f16*)alloc(64L*320*2);  cwx[i]=(f16*)alloc(64L*320*2);
  }

  hipMemsetAsync(h16[0], 0, (long)ROWS*64*2, stream);
  hipMemsetAsync(h16[1], 0, (long)ROWS*64*2, stream);
  hipMemsetAsync(h32[0], 0, (long)ROWS*64*4, stream);
  hipMemsetAsync(h32[1], 0, (long)ROWS*64*4, stream);
  hipMemsetAsync(xdec,   0, (long)ROWS*2, stream);
  hipMemsetAsync(xdect,  0, 131072L*2, stream);

  // setup: W16int[2s] = ilv(A_s); W16int[2s+1] = ilv(2*A_s^2 - I)
  f16* tmpA   = Dh;               // scratch aliases (Dh unused until cells)
  f16* tmpAt  = Dh + 2L*MATH;
  f16* tmpAti = Dh + 4L*MATH;
  f16* tmpSq  = Dh + 5L*MATH;
  k_cast_sup<<<(2*MATH+255)/256, 256, 0, stream>>>(sup, tmpA);
  for (int s=0;s<2;s++) {
    k_transpose<<<dim3(16,16),256,0,stream>>>(tmpA + (long)s*MATH, tmpAt + (long)s*MATH, 1024, 1024);
    k_ilv<<<4096,256,0,stream>>>(tmpA + (long)s*MATH, W16int + (long)(2*s)*MATH);
  }
  for (int s=0;s<2;s++) {
    k_ilv<<<4096,256,0,stream>>>(tmpAt + (long)s*MATH, tmpAti);
    DiffP mp{};
    mp.A0 = W16int + (long)(2*s)*MATH; mp.A1 = mp.A0; mp.a0tr = 0; mp.a1tr = 0; mp.nt0 = 8;
    mp.B = tmpAti; mp.out0 = tmpSq; mp.wsq = 1;
    gemm_diff<<<dim3(8,8),256,0,stream>>>(mp);
    k_ilv<<<4096,256,0,stream>>>(tmpSq, W16int + (long)(2*s+1)*MATH);
  }
  k_pack_x<<<(NT*ROWS+255)/256,256,0,stream>>>(inputs, xenc, xet);
  const int fs[4]  = {65,128,65,128};
  const int xfs[4] = {1,64,1,64};
  for (int i=0;i<4;i++) {
    k_split_w_t<<<(5*fs[i]*128+255)/256,256,0,stream>>>(gwp[i], gwh[i], gwx[i], fs[i], xfs[i], 128);
    k_split_w_t<<<(5*fs[i]*64 +255)/256,256,0,stream>>>(cwp[i], cwh[i], cwx[i], fs[i], xfs[i], 64);
  }

  auto run_cell = [&](const f16* xraw, const f16* xA, int xf,
                      f16* h16c, float* h32c, int wi) {
    // diffusion of h (+x)
    DiffP dp{};
    dp.A0 = h16c; dp.a0tr = 1; dp.nt0 = 32; dp.B = W16int; dp.out0 = Dh; dp.wsq = 0;
    int gx;
    if (xf == 64) { dp.A1 = xA; dp.a1tr = 1; dp.out1 = Dx;  dp.mode_x = 0; gx = 64; }
    else          { dp.A1 = xA; dp.a1tr = 0; dp.out1 = Dx0; dp.mode_x = 2; gx = 33; }
    gemm_diff<<<dim3(gx, 32), 256, 0, stream>>>(dp);
    // gate
    CellP gp{};
    gp.ta.p[0] = h16c; for (int q=1;q<5;q++) gp.ta.p[q] = Dh + (long)(q-1)*SLOT;
    gp.wa = gwh[wi]; gp.bias = gbp[wi];
    gp.h32in = h32c; gp.rh = rh; gp.u32 = u32;
    if (xf == 64) {
      gp.nseg = 2; gp.xf1 = 0;
      gp.tb.p[0] = xraw; for (int q=1;q<5;q++) gp.tb.p[q] = Dx + (long)(q-1)*SLOT;
      gp.wb = gwx[wi];
    } else {
      gp.nseg = 1; gp.xf1 = 1;
      gp.xq.p[0] = xraw; for (int q=1;q<5;q++) gp.xq.p[q] = Dx0 + (long)(q-1)*ROWS;
      gp.wx0 = gwx[wi];
    }
    cell_gemm<128,1><<<512, 256, 0, stream>>>(gp);
    // diffusion of rh
    DiffP dp2{};
    dp2.A0 = rh; dp2.a0tr = 1; dp2.A1 = rh; dp2.a1tr = 1; dp2.nt0 = 32;
    dp2.B = W16int; dp2.out0 = Dh; dp2.wsq = 0;
    gemm_diff<<<dim3(32, 32), 256, 0, stream>>>(dp2);
    // candidate + GRU update
    CellP cp{};
    cp.ta.p[0] = rh; for (int q=1;q<5;q++) cp.ta.p[q] = Dh + (long)(q-1)*SLOT;
    cp.wa = cwh[wi]; cp.bias = cbp[wi];
    cp.u32 = u32; cp.h32io = h32c; cp.h16io = h16c;
    if (xf == 64) {
      cp.nseg = 2; cp.xf1 = 0;
      cp.tb.p[0] = xraw; for (int q=1;q<5;q++) cp.tb.p[q] = Dx + (long)(q-1)*SLOT;
      cp.wb = cwx[wi];
    } else {
      cp.nseg = 1; cp.xf1 = 1;
      cp.xq.p[0] = xraw; for (int q=1;q<5;q++) cp.xq.p[q] = Dx0 + (long)(q-1)*ROWS;
      cp.wx0 = cwx[wi];
    }
    cell_gemm<64,0><<<512, 256, 0, stream>>>(cp);
  };

  for (int t=0;t<NT;t++) {
    run_cell(xenc + (long)t*ROWS, xet + (long)t*131072, 1, h16[0], h32[0], 0);
    run_cell(h16[0], h16[0],                           64, h16[1], h32[1], 1);
  }
  for (int s=0;s<NHOR;s++) {
    run_cell(xdec,   xdect,   1, h16[0], h32[0], 2);
    run_cell(h16[0], h16[0], 64, h16[1], h32[1], 3);
    k_proj<<<ROWS/256, 256, 0, stream>>>(h32[1], pw, pb, out + (long)s*ROWS, xdec, xdect);
  }
}